// Round 8
// baseline (452.347 us; speedup 1.0000x reference)
//
#include <hip/hip_runtime.h>
#include <hip/hip_fp16.h>

typedef unsigned int u32;
typedef unsigned short u16;
typedef __attribute__((ext_vector_type(4))) _Float16 half4;
typedef __attribute__((ext_vector_type(8))) short bf16x8;   // 8 bf16 in 4 VGPRs
typedef __attribute__((ext_vector_type(4))) float f32x4;

#define NPTS 4096
#define DIM  64
#define NB   32          // 4096/128
#define TS   128
#define NBLK 528         // NB*(NB+1)/2 upper-tri blocks
#define WLO16 0x4140u    // window low: float bits 0x41400000 = 12.0
#define NWBIN 832        // t16 in [0x4140, 0x4480) -> D in [12, 1024)

// map linear upper-tri block id -> (by,bx), bx>=by
__device__ __forceinline__ void bmap(int b, int& by, int& bx){
  by = 0;
  while (b >= NB - by){ b -= NB - by; by++; }
  bx = by + b;
}

// fp32 -> bf16 bits, round-nearest-even (no NaN in this data)
__device__ __forceinline__ u16 f2bf(float x){
  u32 u = __float_as_uint(x);
  return (u16)((u + 0x7fffu + ((u>>16)&1u)) >> 16);
}

// ---------- pre-pass: X,Y -> bf16 rows + exact fp32 squared norms ----------
__global__ __launch_bounds__(256) void convert_k(const float* __restrict__ X, const float* __restrict__ Y,
                                                 u16* __restrict__ Xbf, float* __restrict__ Gall){
  int t = blockIdx.x*256 + threadIdx.x;     // 8192 threads, one row each
  int z = t >> 12, row = t & 4095;
  const float* src = (z ? Y : X) + (size_t)row*DIM;
  u16* dst = Xbf + (size_t)t*DIM;
  float g = 0.f;
#pragma unroll
  for (int k=0;k<DIM;k+=4){
    float4 f = *(const float4*)(src+k);
    g = fmaf(f.x,f.x,g); g = fmaf(f.y,f.y,g); g = fmaf(f.z,f.z,g); g = fmaf(f.w,f.w,g);
    ushort4 h; h.x=f2bf(f.x); h.y=f2bf(f.y); h.z=f2bf(f.z); h.w=f2bf(f.w);
    *(ushort4*)(dst+k) = h;
  }
  Gall[t] = g;
}

// ---------- MFMA D blocks from prepacked bf16; fp16 transposed store; fused hist ----------
// A-op/B-op: lane holds row (nl) of the staged 16-row group, k = q*8+j  (validated round 7)
// C/D: col = nl, row = q*4 + reg                                        (validated round 7)
// Stored tile S[r][c] = D[i0+c][j0+r]  (transposed; D symmetric so downstream just swaps sides)
__global__ __launch_bounds__(256,3) void dcompute(const u16* __restrict__ Xbf, const float* __restrict__ Gall,
                                                  _Float16* __restrict__ wsD, u32* __restrict__ hist16)
{
  __shared__ u32 lh[NWBIN+2];
  int z = blockIdx.y;
  int bid = blockIdx.x;
  _Float16* Dst = wsD + (size_t)(z*NBLK + bid)*(TS*TS);
  int by,bx; bmap(bid,by,bx);
  bool isdiag = (by==bx);
  int i0 = by*TS, j0 = bx*TS;
  int tid = threadIdx.x;
  for (int t=tid; t<NWBIN+2; t+=256) lh[t]=0;
  __syncthreads();

  int w = tid>>6, lane = tid&63, q = lane>>4, nl = lane&15;
  const bf16x8* Xb = (const bf16x8*)Xbf + (size_t)z*NPTS*8;   // 8 frags (of 8 bf16) per row
  const float* Gz = Gall + z*NPTS;

  f32x4 acc[2][8];
#pragma unroll
  for (int a=0;a<2;a++)
#pragma unroll
    for (int b=0;b<8;b++) acc[a][b] = (f32x4)0.0f;

  int rowA0 = i0 + (w*2+0)*16 + nl;
  int rowA1 = i0 + (w*2+1)*16 + nl;
  float ga[2] = { Gz[rowA0], Gz[rowA1] };
  float gbl[8];
#pragma unroll
  for (int tb=0; tb<8; tb++) gbl[tb] = Gz[j0 + tb*16 + nl];

#pragma unroll
  for (int kh=0; kh<2; kh++){
    bf16x8 afr[2];
    afr[0] = Xb[(size_t)rowA0*8 + kh*4 + q];
    afr[1] = Xb[(size_t)rowA1*8 + kh*4 + q];
#pragma unroll
    for (int tb=0; tb<8; tb++){
      bf16x8 bfr = Xb[(size_t)(j0 + tb*16 + nl)*8 + kh*4 + q];
      acc[0][tb] = __builtin_amdgcn_mfma_f32_16x16x32_bf16(afr[0], bfr, acc[0][tb], 0,0,0);
      acc[1][tb] = __builtin_amdgcn_mfma_f32_16x16x32_bf16(afr[1], bfr, acc[1][tb], 0,0,0);
    }
  }

#pragma unroll
  for (int ta=0;ta<2;ta++){
    int rt = w*2+ta;
    float gAm[4];
#pragma unroll
    for (int r=0;r<4;r++) gAm[r] = __shfl(ga[ta], q*4+r, 64);
#pragma unroll
    for (int tb=0;tb<8;tb++){
      int jl = tb*16 + nl;
      half4 hv;
#pragma unroll
      for (int r=0;r<4;r++){
        int il = rt*16 + q*4 + r;
        float Dv = (gAm[r] + gbl[tb]) - 2.0f*acc[ta][tb][r];
        if (isdiag && il==jl) Dv = 0.0f;     // exact K_ii = 1
        hv[r] = (_Float16)Dv;
        if (!isdiag || jl > il){
          u32 t16 = __float_as_uint(Dv) >> 16;
          u32 bin = (t16 < WLO16) ? 0u
                  : (t16 >= WLO16+NWBIN) ? (u32)(NWBIN+1)
                  : (t16 - WLO16 + 1u);
          atomicAdd(&lh[bin], 1u);
        }
      }
      *(half4*)(Dst + (size_t)jl*TS + rt*16 + q*4) = hv;   // transposed, 8B store
    }
  }
  __syncthreads();
  for (int t=tid; t<NWBIN+2; t+=256){
    u32 c = lh[t];
    if (c) atomicAdd(&hist16[z*(NWBIN+2) + t], c);
  }
}

// ---------- interpolated median from windowed hist + zero all tail state ----------
__global__ __launch_bounds__(256) void scan16i(const u32* __restrict__ hist16,
                                               float* __restrict__ scal,
                                               double* __restrict__ rowK, double* __restrict__ rowL,
                                               double* __restrict__ sums, u32* __restrict__ counter,
                                               u32 k1, u32 k2){
  int z = blockIdx.x;
  int tid = threadIdx.x;
  if (z==0){
    for (int i=tid;i<NPTS;i+=256) rowK[i]=0.0;
    if (tid<8) sums[tid]=0.0;
    if (tid==8) *counter=0u;
  } else {
    for (int i=tid;i<NPTS;i+=256) rowL[i]=0.0;
  }
  __shared__ u32 v[NWBIN+2];
  for (int t=tid; t<NWBIN+2; t+=256) v[t] = hist16[z*(NWBIN+2)+t];
  __syncthreads();
  if (tid==0){
    double vals[2]; u32 ks[2] = {k1,k2};
    u32 acc = 0;
    int ww = 0;
    for (int b=0;b<NWBIN+2 && ww<2;b++){
      u32 c = v[b];
      while (ww<2 && ks[ww] < acc + c){
        double lo, hi;
        if (b==0){ lo = 12.0; hi = 12.0; }
        else if (b==NWBIN+1){ lo = 1024.0; hi = 1024.0; }
        else {
          u32 t16 = WLO16 + (u32)b - 1u;
          lo = (double)__uint_as_float(t16<<16);
          hi = (double)__uint_as_float((t16+1u)<<16);
        }
        double frac = ((double)(ks[ww]-acc) + 0.5) / (double)(c ? c : 1u);
        vals[ww] = lo + (hi-lo)*frac;
        ww++;
      }
      acc += c;
    }
    float med = (float)(0.5*(vals[0]+vals[1]));
    float wd = sqrtf(0.5f*med);
    scal[z] = 2.0f*wd*wd;
  }
}

// ---------- row/col sums of exp(-D/den), fp64; half-tile blocks; tile totals -> sums[5+z] ----------
// stored tile S[r][c] = K-matrix index [i0+c][j0+r]: row side = j0, col side = i0
__global__ __launch_bounds__(256) void rowsum_k(const _Float16* __restrict__ wsD, const float* __restrict__ scal,
                                                double* __restrict__ rowK, double* __restrict__ rowL,
                                                double* __restrict__ sums){
  int z = blockIdx.y;
  int b = blockIdx.x >> 1, half = blockIdx.x & 1;
  int by,bx; bmap(b,by,bx);
  const half4* base4 = (const half4*)(wsD + (size_t)(z*NBLK+b)*(TS*TS));
  double* rowS = z ? rowL : rowK;
  float den = scal[z];
  int i0 = by*TS, j0 = bx*TS;
  int g = threadIdx.x >> 5, l = threadIdx.x & 31;
  half4 dv[8];
#pragma unroll
  for (int rr=0; rr<8; rr++) dv[rr] = base4[(size_t)(half*64 + g*8 + rr)*32 + l];
  double c0=0,c1=0,c2=0,c3=0, tot=0;
#pragma unroll
  for (int rr=0; rr<8; rr++){
    float e0 = expf(-(float)dv[rr][0]/den), e1 = expf(-(float)dv[rr][1]/den);
    float e2 = expf(-(float)dv[rr][2]/den), e3 = expf(-(float)dv[rr][3]/den);
    double sr = (double)e0 + (double)e1 + (double)e2 + (double)e3;
    c0 += e0; c1 += e1; c2 += e2; c3 += e3;
    for (int off=16; off>0; off>>=1) sr += __shfl_down(sr, off, 32);
    if (l==0){ atomicAdd(&rowS[j0 + half*64 + g*8 + rr], sr); tot += sr; }
  }
  if (bx != by){   // off-diag: also credit column (i-side) sums
    atomicAdd(&rowS[i0 + l*4 + 0], c0);
    atomicAdd(&rowS[i0 + l*4 + 1], c1);
    atomicAdd(&rowS[i0 + l*4 + 2], c2);
    atomicAdd(&rowS[i0 + l*4 + 3], c3);
  }
  // block partial of the grand total (weight 2 for off-diag tiles)
  __shared__ double sg[8];
  if (l==0) sg[g] = tot;
  __syncthreads();
  if (threadIdx.x==0){
    double t = sg[0]+sg[1]+sg[2]+sg[3]+sg[4]+sg[5]+sg[6]+sg[7];
    atomicAdd(&sums[5+z], (bx==by) ? t : 2.0*t);
  }
}

// ---------- wave-parallel regularized lower incomplete gamma P(a,x) ----------
__device__ double gammainc_wave(double a, double x, double lga, int lane){
  double C = 1.0/a;
  double psum = 0.0;
  for (int b=0;b<8192;b++){
    double k = (double)(b*64 + lane + 1);
    double rr = x/(a+k);
    double pp = rr;
#pragma unroll
    for (int s=1;s<64;s<<=1){
      double t = __shfl_up(pp, s, 64);
      if (lane >= s) pp *= t;
    }
    double c = C*pp;
    psum += c;
    double clast = __shfl(c, 63, 64);
    double rlast = __shfl(rr, 63, 64);
    C = clast;
    if (rlast < 1.0 && clast*rlast/(1.0-rlast) < 1e-17) break;
  }
#pragma unroll
  for (int s=1;s<64;s<<=1) psum += __shfl_xor(psum, s, 64);
  double total = 1.0/a + psum;
  return exp(-x + a*log(x) - lga) * total;
}

// ---------- fused centered-product (32-row strips) + last-block finalize ----------
__global__ __launch_bounds__(256) void final_pass3(const _Float16* __restrict__ wsD,
                                                   const float* __restrict__ scal,
                                                   const double* __restrict__ rowK,
                                                   const double* __restrict__ rowL,
                                                   double* __restrict__ sums,
                                                   u32* __restrict__ counter,
                                                   float* __restrict__ out){
  int tid = threadIdx.x;
  int b = blockIdx.x >> 2, strip = blockIdx.x & 3;
  int by,bx; bmap(b,by,bx);
  const half4* X4 = (const half4*)(wsD + (size_t)b*(TS*TS));
  const half4* Y4 = (const half4*)(wsD + (size_t)(NBLK+b)*(TS*TS));
  float denx = scal[0], deny = scal[1];
  int i0=by*TS, j0=bx*TS;
  const double inv_n = 1.0/(double)NPTS;
  double totK = sums[5], totL = sums[6];          // written by rowsum_k (prev dispatch)
  double tmK = totK*(inv_n*inv_n), tmL = totL*(inv_n*inv_n);
  int g = tid>>5, l = tid&31;
  double cmK[4], cmL[4];                          // col side = i0
#pragma unroll
  for (int c=0;c<4;c++){ cmK[c]=rowK[i0+l*4+c]*inv_n - tmK; cmL[c]=rowL[i0+l*4+c]*inv_n - tmL; }
  double w = (bx==by)?1.0:2.0;
  double S1=0,S2=0,trV=0,trK=0,trL=0;
  for (int c4=0; c4<1; c4++){}                    // (kept structure simple: one strip of 32 rows)
  {
    half4 dx[4], dy[4];
#pragma unroll
    for (int blk=0; blk<1; blk++){}
    for (int u4=0; u4<1; u4++){}
  }
  for (int uu=0; uu<4; uu++){
    half4 dx, dy;
    int r = strip*32 + g*4 + uu;                  // stored row = j-side index
    dx = X4[(size_t)r*32 + l];
    dy = Y4[(size_t)r*32 + l];
    double rmKr = rowK[j0+r]*inv_n, rmLr = rowL[j0+r]*inv_n;
    float ka[4] = {expf(-(float)dx[0]/denx), expf(-(float)dx[1]/denx),
                   expf(-(float)dx[2]/denx), expf(-(float)dx[3]/denx)};
    float la[4] = {expf(-(float)dy[0]/deny), expf(-(float)dy[1]/deny),
                   expf(-(float)dy[2]/deny), expf(-(float)dy[3]/deny)};
#pragma unroll
    for (int c=0;c<4;c++){
      double kc = ((double)ka[c] - rmKr) - cmK[c];
      double lc = ((double)la[c] - rmLr) - cmL[c];
      double prod = kc*lc;
      S1 += w*prod;
      double vv = (prod*prod)*(1.0/36.0);
      S2 += w*vv;
      if (bx==by && (l*4+c)==r){ trV += vv; trK += (double)ka[c]; trL += (double)la[c]; }
    }
  }
  __shared__ double red[4][5];
  double vals[5]={S1,S2,trV,trK,trL};
  int lane = tid & 63, wv = tid >> 6;
#pragma unroll
  for (int v=0;v<5;v++){
    double x = vals[v];
#pragma unroll
    for (int s2=1;s2<64;s2<<=1) x += __shfl_xor(x, s2, 64);
    if (lane==0) red[wv][v]=x;
  }
  __syncthreads();
  if (tid < 5)
    atomicAdd(&sums[tid], red[0][tid]+red[1][tid]+red[2][tid]+red[3][tid]);
  __threadfence();
  __shared__ int lastflag;
  if (tid==0) lastflag = (atomicAdd(counter,1u) == (u32)(NBLK*4-1)) ? 1 : 0;
  __syncthreads();
  if (!lastflag || tid >= 64) return;

  // ---- last block: finalize (coherent reads via atomic RMW of +0.0) ----
  int fl = tid;
  double fS1 = atomicAdd(&sums[0],0.0);
  double fS2 = atomicAdd(&sums[1],0.0);
  double ftrV= atomicAdd(&sums[2],0.0);
  double ftrK= atomicAdd(&sums[3],0.0);
  double ftrL= atomicAdd(&sums[4],0.0);
  const double n = (double)NPTS;
  double testStat = fS1/n;
  double varHSIC = (fS2 - ftrV)/n/(n-1.0);
  varHSIC = varHSIC*72.0*(n-4.0)*(n-5.0)/n/(n-1.0)/(n-2.0)/(n-3.0);
  double muX = (totK-ftrK)/n/(n-1.0);
  double muY = (totL-ftrL)/n/(n-1.0);
  double mHSIC = (1.0 + muX*muY - muX - muY)/n;
  double al = mHSIC*mHSIC/varHSIC;
  double bet = varHSIC*n/mHSIC;
  double p = (double)((float)(1.0-0.8));
  double lga = lgamma(al);
  double lo = 0.0, hi = al + 10.0*sqrt(al) + 100.0;
  const double zp = -0.8416212335729142957;  // Phi^-1(0.2)
  double t = 1.0 - 1.0/(9.0*al) + zp/(3.0*sqrt(al));
  double x = al*t*t*t;
  if (!(x > 0.0) || !(x < hi)) x = 0.5*hi;
  for (int it=0; it<2; ++it){
    double P = gammainc_wave(al, x, lga, fl);
    double diff = P - p;
    if (diff < 0.0) lo = x; else hi = x;
    if (fabs(diff) < 1e-12) break;
    double pdf = exp(-x + (al-1.0)*log(x) - lga);
    double nx = x - diff/pdf;
    if (!(nx > lo) || !(nx < hi)) nx = 0.5*(lo+hi);
    x = nx;
  }
  if (fl==0){
    out[0]=(float)testStat;
    out[1]=(float)(bet*x);
  }
}

// ---------- host ----------
extern "C" void kernel_launch(void* const* d_in, const int* in_sizes, int n_in,
                              void* d_out, int out_size, void* d_ws, size_t ws_size,
                              hipStream_t stream) {
  const float* X = (const float*)d_in[0];
  const float* Y = (const float*)d_in[1];
  float* out = (float*)d_out;
  char* ws = (char*)d_ws;

  double* sums    = (double*)ws;                    // 8 doubles @0
  u32*    counter = (u32*)(ws + 64);
  float*  scal    = (float*)(ws + 128);             // 2 floats
  u32*    hist16  = (u32*)(ws + 256);               // [2][834] u32 = 6672 B
  double* rowK    = (double*)(ws + 8192);           // 32 KB
  double* rowL    = (double*)(ws + 8192 + 32768);   // 32 KB
  float*  Gall    = (float*)(ws + 73728);           // 2*4096 fp32 = 32 KB
  u16*    Xbf     = (u16*)(ws + 131072);            // 2*4096*64 bf16 = 1 MB
  _Float16* wsD   = (_Float16*)(ws + (2<<20));      // 2*528*16384 fp16 = 34.6 MB
  size_t need = (size_t)(2<<20) + (size_t)2*NBLK*(TS*TS)*2;

  if (ws_size < need) return;   // harness provides enough (verified rounds 2-7)

  hipMemsetAsync(ws + 256, 0, 6672, stream);        // hist16 only

  const u32 K1 = 4193279u, K2 = 4193280u;  // m = 4096*4095/2; median = avg of ranks m/2-1, m/2

  convert_k<<<32,256,0,stream>>>(X, Y, Xbf, Gall);
  dcompute<<<dim3(NBLK,2),256,0,stream>>>(Xbf, Gall, wsD, hist16);
  scan16i<<<2,256,0,stream>>>(hist16, scal, rowK, rowL, sums, counter, K1, K2);
  rowsum_k<<<dim3(2*NBLK,2),256,0,stream>>>(wsD, scal, rowK, rowL, sums);
  final_pass3<<<NBLK*4,256,0,stream>>>(wsD, scal, rowK, rowL, sums, counter, out);
}

// Round 9
// 264.752 us; speedup vs baseline: 1.7086x; 1.7086x over previous
//
#include <hip/hip_runtime.h>

typedef unsigned int u32;
typedef unsigned short u16;
typedef __attribute__((ext_vector_type(8))) short bf16x8;   // 8 bf16 in 4 VGPRs
typedef __attribute__((ext_vector_type(4))) float f32x4;

#define NPTS 4096
#define DIM  64
#define NB   32          // 4096/128
#define TS   128
#define NBLK 528         // NB*(NB+1)/2 upper-tri blocks
#define WLO16 0x4140u    // window low: float bits 0x41400000 = 12.0
#define NWBIN 832        // t16 in [0x4140, 0x4480) -> D in [12, 1024)

// map linear upper-tri block id -> (by,bx), bx>=by
__device__ __forceinline__ void bmap(int b, int& by, int& bx){
  by = 0;
  while (b >= NB - by){ b -= NB - by; by++; }
  bx = by + b;
}

// fp32 -> bf16 bits, round-nearest-even
__device__ __forceinline__ u16 f2bf(float x){
  u32 u = __float_as_uint(x);
  return (u16)((u + 0x7fffu + ((u>>16)&1u)) >> 16);
}

// ---------- pre-pass: X,Y -> bf16 rows + fp32 squared norms ----------
__global__ __launch_bounds__(256) void convert_k(const float* __restrict__ X, const float* __restrict__ Y,
                                                 u16* __restrict__ Xbf, float* __restrict__ Gall){
  int t = blockIdx.x*256 + threadIdx.x;     // 8192 threads, one row each
  int z = t >> 12, row = t & 4095;
  const float* src = (z ? Y : X) + (size_t)row*DIM;
  u16* dst = Xbf + (size_t)t*DIM;
  float g = 0.f;
#pragma unroll
  for (int k=0;k<DIM;k+=4){
    float4 f = *(const float4*)(src+k);
    g = fmaf(f.x,f.x,g); g = fmaf(f.y,f.y,g); g = fmaf(f.z,f.z,g); g = fmaf(f.w,f.w,g);
    ushort4 h; h.x=f2bf(f.x); h.y=f2bf(f.y); h.z=f2bf(f.z); h.w=f2bf(f.w);
    *(ushort4*)(dst+k) = h;
  }
  Gall[t] = g;
}

// ---------- MFMA D sub-tile: 16 rows (rowA group) x 128 cols, C layout ----------
// A/B-op: lane holds row nl of its 16-row group, k = q*8+j   (validated rounds 7-8, absmax 0.0)
// C/D  : col = nl, row = q*4 + r                             (validated rounds 7-8)
__device__ __forceinline__ void dtile1(const bf16x8* __restrict__ Xb, const float* __restrict__ Gz,
                                       int rowA, int j0, int q, int nl, float (&Dv)[8][4])
{
  f32x4 acc[8];
#pragma unroll
  for (int b=0;b<8;b++) acc[b] = (f32x4)0.0f;
#pragma unroll
  for (int kh=0; kh<2; kh++){
    bf16x8 afr = Xb[(size_t)rowA*8 + kh*4 + q];
#pragma unroll
    for (int tb=0; tb<8; tb++){
      bf16x8 bfr = Xb[(size_t)(j0 + tb*16 + nl)*8 + kh*4 + q];
      acc[tb] = __builtin_amdgcn_mfma_f32_16x16x32_bf16(afr, bfr, acc[tb], 0,0,0);
    }
  }
  float ga = Gz[rowA];
  float gAm[4];
#pragma unroll
  for (int r=0;r<4;r++) gAm[r] = __shfl(ga, q*4+r, 64);
#pragma unroll
  for (int tb=0;tb<8;tb++){
    float gb = Gz[j0 + tb*16 + nl];
#pragma unroll
    for (int r=0;r<4;r++)
      Dv[tb][r] = (gAm[r] + gb) - 2.0f*acc[tb][r];
  }
}

// ---------- pass 1: histogram only (no D store) ----------
__global__ __launch_bounds__(256,2) void hist_k(const u16* __restrict__ Xbf, const float* __restrict__ Gall,
                                                u32* __restrict__ hist16){
  __shared__ u32 lh[NWBIN+2];
  int z = blockIdx.y, bid = blockIdx.x, tid = threadIdx.x;
  int by,bx; bmap(bid,by,bx);
  bool isdiag = (by==bx);
  int i0=by*TS, j0=bx*TS;
  for (int t=tid;t<NWBIN+2;t+=256) lh[t]=0;
  __syncthreads();
  int w=tid>>6, lane=tid&63, q=lane>>4, nl=lane&15;
  const bf16x8* Xb = (const bf16x8*)Xbf + (size_t)z*NPTS*8;
  const float* Gz = Gall + z*NPTS;
#pragma unroll
  for (int ta=0;ta<2;ta++){
    int rt = w*2+ta;
    float Dv[8][4];
    dtile1(Xb, Gz, i0 + rt*16 + nl, j0, q, nl, Dv);
#pragma unroll
    for (int tb=0;tb<8;tb++){
      int jl = tb*16+nl;
#pragma unroll
      for (int r=0;r<4;r++){
        int il = rt*16+q*4+r;
        if (!isdiag || jl > il){
          u32 t16 = __float_as_uint(Dv[tb][r]) >> 16;
          u32 bin = (t16 < WLO16) ? 0u
                  : (t16 >= WLO16+NWBIN) ? (u32)(NWBIN+1)
                  : (t16 - WLO16 + 1u);
          atomicAdd(&lh[bin], 1u);
        }
      }
    }
  }
  __syncthreads();
  for (int t=tid;t<NWBIN+2;t+=256){ u32 c=lh[t]; if(c) atomicAdd(&hist16[z*(NWBIN+2)+t], c); }
}

// ---------- interpolated median + zero rowK/rowL ----------
__global__ __launch_bounds__(256) void scan16i(const u32* __restrict__ hist16,
                                               float* __restrict__ scal,
                                               double* __restrict__ rowK, double* __restrict__ rowL,
                                               u32 k1, u32 k2){
  int z = blockIdx.x;
  int tid = threadIdx.x;
  double* rz = z ? rowL : rowK;
  for (int i=tid;i<NPTS;i+=256) rz[i]=0.0;
  __shared__ u32 v[NWBIN+2];
  for (int t=tid; t<NWBIN+2; t+=256) v[t] = hist16[z*(NWBIN+2)+t];
  __syncthreads();
  if (tid==0){
    double vals[2]; u32 ks[2] = {k1,k2};
    u32 acc = 0;
    int ww = 0;
    for (int b=0;b<NWBIN+2 && ww<2;b++){
      u32 c = v[b];
      while (ww<2 && ks[ww] < acc + c){
        double lo, hi;
        if (b==0){ lo = 12.0; hi = 12.0; }
        else if (b==NWBIN+1){ lo = 1024.0; hi = 1024.0; }
        else {
          u32 t16 = WLO16 + (u32)b - 1u;
          lo = (double)__uint_as_float(t16<<16);
          hi = (double)__uint_as_float((t16+1u)<<16);
        }
        double frac = ((double)(ks[ww]-acc) + 0.5) / (double)(c ? c : 1u);
        vals[ww] = lo + (hi-lo)*frac;
        ww++;
      }
      acc += c;
    }
    float med = (float)(0.5*(vals[0]+vals[1]));
    float wd = sqrtf(0.5f*med);
    scal[z] = 2.0f*wd*wd;
  }
}

// ---------- pass 2: recompute D, exp, row/col sums (distinct-address fp64 atomics only) ----------
__global__ __launch_bounds__(256,2) void rowsum_k(const u16* __restrict__ Xbf, const float* __restrict__ Gall,
                                                  const float* __restrict__ scal,
                                                  double* __restrict__ rowK, double* __restrict__ rowL){
  int z = blockIdx.y, bid = blockIdx.x, tid = threadIdx.x;
  int by,bx; bmap(bid,by,bx);
  bool isdiag = (by==bx);
  int i0=by*TS, j0=bx*TS;
  int w=tid>>6, lane=tid&63, q=lane>>4, nl=lane&15;
  const bf16x8* Xb = (const bf16x8*)Xbf + (size_t)z*NPTS*8;
  const float* Gz = Gall + z*NPTS;
  double* rowS = z ? rowL : rowK;
  float negi = -1.0f/scal[z];
  double cs[8] = {0,0,0,0,0,0,0,0};
#pragma unroll
  for (int ta=0;ta<2;ta++){
    int rt = w*2+ta;
    float Dv[8][4];
    dtile1(Xb, Gz, i0 + rt*16 + nl, j0, q, nl, Dv);
    double rs[4] = {0,0,0,0};
#pragma unroll
    for (int tb=0;tb<8;tb++){
      int jl = tb*16+nl;
#pragma unroll
      for (int r=0;r<4;r++){
        int il = rt*16+q*4+r;
        float d = Dv[tb][r];
        if (isdiag && il==jl) d = 0.f;      // exact K_ii = 1
        float e = expf(d*negi);
        rs[r] += e; cs[tb] += e;
      }
    }
    // full row sums: reduce across nl lanes (cols)
#pragma unroll
    for (int r=0;r<4;r++){
      double v2 = rs[r];
      v2 += __shfl_xor(v2,1,64); v2 += __shfl_xor(v2,2,64);
      v2 += __shfl_xor(v2,4,64); v2 += __shfl_xor(v2,8,64);
      if (nl==0) atomicAdd(&rowS[i0 + rt*16 + q*4 + r], v2);
    }
  }
  if (!isdiag){
    // symmetric credit: col sums -> rows j0+...; reduce across q groups
#pragma unroll
    for (int tb=0;tb<8;tb++){
      double v2 = cs[tb];
      v2 += __shfl_xor(v2,16,64); v2 += __shfl_xor(v2,32,64);
      if (q==0) atomicAdd(&rowS[j0 + tb*16 + nl], v2);
    }
  }
}

// ---------- totals of rowK/rowL ----------
__global__ __launch_bounds__(256) void reduce_rows(const double* __restrict__ rowK,
                                                   const double* __restrict__ rowL,
                                                   double* __restrict__ sums){
  __shared__ double sd[256];
  int t=threadIdx.x;
  double s=0; for(int i=t;i<NPTS;i+=256) s+=rowK[i];
  sd[t]=s; __syncthreads();
  for(int off=128;off>0;off>>=1){ if(t<off) sd[t]+=sd[t+off]; __syncthreads(); }
  if(t==0) sums[0]=sd[0];
  __syncthreads();
  s=0; for(int i=t;i<NPTS;i+=256) s+=rowL[i];
  sd[t]=s; __syncthreads();
  for(int off=128;off>0;off>>=1){ if(t<off) sd[t]+=sd[t+off]; __syncthreads(); }
  if(t==0) sums[1]=sd[0];
}

// ---------- pass 3: recompute both D tiles, centered products -> per-block partials ----------
__global__ __launch_bounds__(256,2) void final_k(const u16* __restrict__ Xbf, const float* __restrict__ Gall,
                                                 const float* __restrict__ scal,
                                                 const double* __restrict__ rowK,
                                                 const double* __restrict__ rowL,
                                                 const double* __restrict__ sums,
                                                 double* __restrict__ partials){
  int b = blockIdx.x, tid = threadIdx.x;
  int by,bx; bmap(b,by,bx);
  bool isdiag = (by==bx);
  int i0=by*TS, j0=bx*TS;
  int w=tid>>6, lane=tid&63, q=lane>>4, nl=lane&15;
  const bf16x8* Xb = (const bf16x8*)Xbf;
  const bf16x8* Yb = (const bf16x8*)Xbf + (size_t)NPTS*8;
  const float* Gx = Gall;
  const float* Gy = Gall + NPTS;
  const double inv_n = 1.0/(double)NPTS;
  double tmK = sums[0]*(inv_n*inv_n), tmL = sums[1]*(inv_n*inv_n);
  float negx = -1.0f/scal[0], negy = -1.0f/scal[1];

  // column-side means (shared across ta)
  double cmK[8], cmL[8];
#pragma unroll
  for (int tb=0;tb<8;tb++){
    int j = j0 + tb*16 + nl;
    cmK[tb] = rowK[j]*inv_n - tmK;
    cmL[tb] = rowL[j]*inv_n - tmL;
  }
  double wgt = isdiag ? 1.0 : 2.0;
  double S1=0, S2=0, trV=0;
#pragma unroll
  for (int ta=0;ta<2;ta++){
    int rt = w*2+ta;
    float kx[8][4];
    {
      float Dv[8][4];
      dtile1(Xb, Gx, i0 + rt*16 + nl, j0, q, nl, Dv);
#pragma unroll
      for (int tb=0;tb<8;tb++)
#pragma unroll
        for (int r=0;r<4;r++){
          int il = rt*16+q*4+r, jl = tb*16+nl;
          float d = Dv[tb][r];
          if (isdiag && il==jl) d = 0.f;
          kx[tb][r] = expf(d*negx);
        }
    }
    float Dy[8][4];
    dtile1(Yb, Gy, i0 + rt*16 + nl, j0, q, nl, Dy);
#pragma unroll
    for (int r=0;r<4;r++){
      int i = i0 + rt*16 + q*4 + r;
      double rmKi = rowK[i]*inv_n, rmLi = rowL[i]*inv_n;
#pragma unroll
      for (int tb=0;tb<8;tb++){
        int il = rt*16+q*4+r, jl = tb*16+nl;
        float d = Dy[tb][r];
        if (isdiag && il==jl) d = 0.f;
        float lv = expf(d*negy);
        double kc = ((double)kx[tb][r] - rmKi) - cmK[tb];
        double lc = ((double)lv - rmLi) - cmL[tb];
        double prod = kc*lc;
        S1 += wgt*prod;
        double vv = (prod*prod)*(1.0/36.0);
        S2 += wgt*vv;
        if (isdiag && il==jl) trV += vv;
      }
    }
  }
  __shared__ double red[4][3];
  double vals[3]={S1,S2,trV};
  int wv = tid >> 6;
#pragma unroll
  for (int v=0;v<3;v++){
    double x = vals[v];
#pragma unroll
    for (int s2=1;s2<64;s2<<=1) x += __shfl_xor(x, s2, 64);
    if (lane==0) red[wv][v]=x;
  }
  __syncthreads();
  if (tid < 3)
    partials[(size_t)b*4 + tid] = red[0][tid]+red[1][tid]+red[2][tid]+red[3][tid];
}

// ---------- wave-parallel regularized lower incomplete gamma P(a,x) ----------
__device__ double gammainc_wave(double a, double x, double lga, int lane){
  double C = 1.0/a;
  double psum = 0.0;
  for (int b=0;b<8192;b++){
    double k = (double)(b*64 + lane + 1);
    double rr = x/(a+k);
    double pp = rr;
#pragma unroll
    for (int s=1;s<64;s<<=1){
      double t = __shfl_up(pp, s, 64);
      if (lane >= s) pp *= t;
    }
    double c = C*pp;
    psum += c;
    double clast = __shfl(c, 63, 64);
    double rlast = __shfl(rr, 63, 64);
    C = clast;
    if (rlast < 1.0 && clast*rlast/(1.0-rlast) < 1e-17) break;
  }
#pragma unroll
  for (int s=1;s<64;s<<=1) psum += __shfl_xor(psum, s, 64);
  double total = 1.0/a + psum;
  return exp(-x + a*log(x) - lga) * total;
}

// ---------- reduce partials + Newton ----------
__global__ __launch_bounds__(256) void finalize_k(const double* __restrict__ partials,
                                                  const double* __restrict__ sums,
                                                  float* __restrict__ out)
{
  __shared__ double red[3][4];
  __shared__ double tot[4];
  int tid = threadIdx.x;
  double v0=0,v1=0,v2=0;
  for (int i=tid; i<NBLK; i+=256){
    const double* p = partials + (size_t)i*4;
    v0+=p[0]; v1+=p[1]; v2+=p[2];
  }
  double vals[3]={v0,v1,v2};
  int lane = tid & 63, wv = tid >> 6;
#pragma unroll
  for (int v=0;v<3;v++){
    double x = vals[v];
#pragma unroll
    for (int s2=1;s2<64;s2<<=1) x += __shfl_xor(x, s2, 64);
    if (lane==0) red[v][wv]=x;
  }
  __syncthreads();
  if (tid==0){
#pragma unroll
    for (int v=0;v<3;v++) tot[v] = red[v][0]+red[v][1]+red[v][2]+red[v][3];
  }
  __syncthreads();
  if (tid >= 64) return;

  const double n = (double)NPTS;
  double totK=sums[0], totL=sums[1];
  double S1=tot[0], S2=tot[1], trV=tot[2];
  double testStat = S1/n;
  double varHSIC = (S2 - trV)/n/(n-1.0);
  varHSIC = varHSIC*72.0*(n-4.0)*(n-5.0)/n/(n-1.0)/(n-2.0)/(n-3.0);
  double muX = (totK-n)/n/(n-1.0);   // trace(K) = n exactly (diag forced to 1)
  double muY = (totL-n)/n/(n-1.0);
  double mHSIC = (1.0 + muX*muY - muX - muY)/n;
  double al = mHSIC*mHSIC/varHSIC;
  double bet = varHSIC*n/mHSIC;
  double p = (double)((float)(1.0-0.8));
  double lga = lgamma(al);
  double lo = 0.0, hi = al + 10.0*sqrt(al) + 100.0;
  const double zp = -0.8416212335729142957;  // Phi^-1(0.2)
  double t = 1.0 - 1.0/(9.0*al) + zp/(3.0*sqrt(al));
  double x = al*t*t*t;
  if (!(x > 0.0) || !(x < hi)) x = 0.5*hi;
  for (int it=0; it<2; ++it){
    double P = gammainc_wave(al, x, lga, lane);
    double diff = P - p;
    if (diff < 0.0) lo = x; else hi = x;
    if (fabs(diff) < 1e-12) break;
    double pdf = exp(-x + (al-1.0)*log(x) - lga);
    double nx = x - diff/pdf;
    if (!(nx > lo) || !(nx < hi)) nx = 0.5*(lo+hi);
    x = nx;
  }
  if (lane==0){
    out[0]=(float)testStat;
    out[1]=(float)(bet*x);
  }
}

// ---------- host ----------
extern "C" void kernel_launch(void* const* d_in, const int* in_sizes, int n_in,
                              void* d_out, int out_size, void* d_ws, size_t ws_size,
                              hipStream_t stream) {
  const float* X = (const float*)d_in[0];
  const float* Y = (const float*)d_in[1];
  float* out = (float*)d_out;
  char* ws = (char*)d_ws;

  double* sums     = (double*)ws;                    // 2 doubles @0
  float*  scal     = (float*)(ws + 128);             // 2 floats
  u32*    hist16   = (u32*)(ws + 256);               // [2][834] u32 = 6672 B
  double* rowK     = (double*)(ws + 8192);           // 32 KB
  double* rowL     = (double*)(ws + 8192 + 32768);   // 32 KB
  float*  Gall     = (float*)(ws + 73728);           // 2*4096 fp32 = 32 KB
  double* partials = (double*)(ws + 106496);         // 528*4 doubles = 16896 B
  u16*    Xbf      = (u16*)(ws + 131072);            // 2*4096*64 bf16 = 1 MB
  size_t need = 131072 + (size_t)2*NPTS*DIM*2;       // ~1.2 MB

  if (ws_size < need) return;

  hipMemsetAsync(ws + 256, 0, 6672, stream);         // hist16 only

  const u32 K1 = 4193279u, K2 = 4193280u;  // m = 4096*4095/2; median = avg of ranks m/2-1, m/2

  convert_k<<<32,256,0,stream>>>(X, Y, Xbf, Gall);
  hist_k<<<dim3(NBLK,2),256,0,stream>>>(Xbf, Gall, hist16);
  scan16i<<<2,256,0,stream>>>(hist16, scal, rowK, rowL, K1, K2);
  rowsum_k<<<dim3(NBLK,2),256,0,stream>>>(Xbf, Gall, scal, rowK, rowL);
  reduce_rows<<<1,256,0,stream>>>(rowK, rowL, sums);
  final_k<<<NBLK,256,0,stream>>>(Xbf, Gall, scal, rowK, rowL, sums, partials);
  finalize_k<<<1,256,0,stream>>>(partials, sums, out);
}

// Round 10
// 189.458 us; speedup vs baseline: 2.3876x; 1.3974x over previous
//
#include <hip/hip_runtime.h>

typedef unsigned int u32;
typedef unsigned short u16;
typedef __attribute__((ext_vector_type(8))) short bf16x8;   // 8 bf16 in 4 VGPRs
typedef __attribute__((ext_vector_type(4))) float f32x4;

#define NPTS 4096
#define DIM  64
#define NB   32          // 4096/128
#define TS   128
#define NBLK 528         // NB*(NB+1)/2 upper-tri blocks
#define WLO16 0x4140u    // window low: float bits 0x41400000 = 12.0
#define NWBIN 832        // t16 in [0x4140, 0x4480) -> D in [12, 1024)

// map linear upper-tri block id -> (by,bx), bx>=by
__device__ __forceinline__ void bmap(int b, int& by, int& bx){
  by = 0;
  while (b >= NB - by){ b -= NB - by; by++; }
  bx = by + b;
}

// fp32 -> bf16 bits, round-nearest-even
__device__ __forceinline__ u16 f2bf(float x){
  u32 u = __float_as_uint(x);
  return (u16)((u + 0x7fffu + ((u>>16)&1u)) >> 16);
}

// ---------- pre-pass: X,Y -> bf16 rows + fp32 squared norms ----------
__global__ __launch_bounds__(256) void convert_k(const float* __restrict__ X, const float* __restrict__ Y,
                                                 u16* __restrict__ Xbf, float* __restrict__ Gall){
  int t = blockIdx.x*256 + threadIdx.x;     // 8192 threads, one row each
  int z = t >> 12, row = t & 4095;
  const float* src = (z ? Y : X) + (size_t)row*DIM;
  u16* dst = Xbf + (size_t)t*DIM;
  float g = 0.f;
#pragma unroll
  for (int k=0;k<DIM;k+=4){
    float4 f = *(const float4*)(src+k);
    g = fmaf(f.x,f.x,g); g = fmaf(f.y,f.y,g); g = fmaf(f.z,f.z,g); g = fmaf(f.w,f.w,g);
    ushort4 h; h.x=f2bf(f.x); h.y=f2bf(f.y); h.z=f2bf(f.z); h.w=f2bf(f.w);
    *(ushort4*)(dst+k) = h;
  }
  Gall[t] = g;
}

// ---------- MFMA D sub-tile: 16 rows x 128 cols (validated rounds 7-9, absmax 0.0) ----------
__device__ __forceinline__ void dtile1(const bf16x8* __restrict__ Xb, const float* __restrict__ Gz,
                                       int rowA, int j0, int q, int nl, float (&Dv)[8][4])
{
  f32x4 acc[8];
#pragma unroll
  for (int b=0;b<8;b++) acc[b] = (f32x4)0.0f;
#pragma unroll
  for (int kh=0; kh<2; kh++){
    bf16x8 afr = Xb[(size_t)rowA*8 + kh*4 + q];
#pragma unroll
    for (int tb=0; tb<8; tb++){
      bf16x8 bfr = Xb[(size_t)(j0 + tb*16 + nl)*8 + kh*4 + q];
      acc[tb] = __builtin_amdgcn_mfma_f32_16x16x32_bf16(afr, bfr, acc[tb], 0,0,0);
    }
  }
  float ga = Gz[rowA];
  float gAm[4];
#pragma unroll
  for (int r=0;r<4;r++) gAm[r] = __shfl(ga, q*4+r, 64);
#pragma unroll
  for (int tb=0;tb<8;tb++){
    float gb = Gz[j0 + tb*16 + nl];
#pragma unroll
    for (int r=0;r<4;r++)
      Dv[tb][r] = (gAm[r] + gb) - 2.0f*acc[tb][r];
  }
}

// ---------- pass 1: histogram only ----------
__global__ __launch_bounds__(256,2) void hist_k(const u16* __restrict__ Xbf, const float* __restrict__ Gall,
                                                u32* __restrict__ hist16){
  __shared__ u32 lh[NWBIN+2];
  int z = blockIdx.y, bid = blockIdx.x, tid = threadIdx.x;
  int by,bx; bmap(bid,by,bx);
  bool isdiag = (by==bx);
  int i0=by*TS, j0=bx*TS;
  for (int t=tid;t<NWBIN+2;t+=256) lh[t]=0;
  __syncthreads();
  int w=tid>>6, lane=tid&63, q=lane>>4, nl=lane&15;
  const bf16x8* Xb = (const bf16x8*)Xbf + (size_t)z*NPTS*8;
  const float* Gz = Gall + z*NPTS;
#pragma unroll
  for (int ta=0;ta<2;ta++){
    int rt = w*2+ta;
    float Dv[8][4];
    dtile1(Xb, Gz, i0 + rt*16 + nl, j0, q, nl, Dv);
#pragma unroll
    for (int tb=0;tb<8;tb++){
      int jl = tb*16+nl;
#pragma unroll
      for (int r=0;r<4;r++){
        int il = rt*16+q*4+r;
        if (!isdiag || jl > il){
          u32 t16 = __float_as_uint(Dv[tb][r]) >> 16;
          u32 bin = (t16 < WLO16) ? 0u
                  : (t16 >= WLO16+NWBIN) ? (u32)(NWBIN+1)
                  : (t16 - WLO16 + 1u);
          atomicAdd(&lh[bin], 1u);
        }
      }
    }
  }
  __syncthreads();
  for (int t=tid;t<NWBIN+2;t+=256){ u32 c=lh[t]; if(c) atomicAdd(&hist16[z*(NWBIN+2)+t], c); }
}

// ---------- parallel select: 4 bins/thread, shuffle prefix, interpolate; zero rowK/rowL ----------
__global__ __launch_bounds__(256) void scan16i(const u32* __restrict__ hist16,
                                               float* __restrict__ scal,
                                               double* __restrict__ rowK, double* __restrict__ rowL,
                                               u32 k1, u32 k2){
  int z = blockIdx.x;
  int tid = threadIdx.x;
  double* rz = z ? rowL : rowK;
  for (int i=tid;i<NPTS;i+=256) rz[i]=0.0;
  __shared__ u32 v[1024];
  __shared__ u32 wsum[4];
  __shared__ double svals[2];
  for (int t=tid;t<1024;t+=256) v[t] = (t<NWBIN+2) ? hist16[z*(NWBIN+2)+t] : 0u;
  __syncthreads();
  uint4 cv = ((const uint4*)v)[tid];
  u32 c4[4] = {cv.x, cv.y, cv.z, cv.w};
  u32 s = c4[0]+c4[1]+c4[2]+c4[3];
  int lane = tid & 63, wv = tid >> 6;
  u32 pre = s;
#pragma unroll
  for (int off=1; off<64; off<<=1){
    u32 t2 = __shfl_up(pre, off, 64);
    if (lane >= off) pre += t2;
  }
  if (lane==63) wsum[wv] = pre;
  __syncthreads();
  u32 base = 0;
  for (int k=0;k<wv;k++) base += wsum[k];
  u32 incl = base + pre, excl = incl - s;
  u32 ks[2] = {k1,k2};
#pragma unroll
  for (int w2=0; w2<2; w2++){
    if (ks[w2] >= excl && ks[w2] < incl){
      u32 acc = excl;
#pragma unroll
      for (int j=0;j<4;j++){
        if (ks[w2] < acc + c4[j]){
          int b = tid*4 + j;
          double lo, hi;
          if (b==0){ lo=12.0; hi=12.0; }
          else if (b>=NWBIN+1){ lo=1024.0; hi=1024.0; }
          else {
            u32 t16 = WLO16 + (u32)b - 1u;
            lo = (double)__uint_as_float(t16<<16);
            hi = (double)__uint_as_float((t16+1u)<<16);
          }
          double frac = ((double)(ks[w2]-acc) + 0.5)/(double)c4[j];
          svals[w2] = lo + (hi-lo)*frac;
          break;
        }
        acc += c4[j];
      }
    }
  }
  __syncthreads();
  if (tid==0){
    float med = (float)(0.5*(svals[0]+svals[1]));
    float wd = sqrtf(0.5f*med);
    scal[z] = 2.0f*wd*wd;
  }
}

// ---------- pass 2: recompute D, exp, row/col sums (distinct-address fp64 atomics only) ----------
__global__ __launch_bounds__(256,2) void rowsum_k(const u16* __restrict__ Xbf, const float* __restrict__ Gall,
                                                  const float* __restrict__ scal,
                                                  double* __restrict__ rowK, double* __restrict__ rowL){
  int z = blockIdx.y, bid = blockIdx.x, tid = threadIdx.x;
  int by,bx; bmap(bid,by,bx);
  bool isdiag = (by==bx);
  int i0=by*TS, j0=bx*TS;
  int w=tid>>6, lane=tid&63, q=lane>>4, nl=lane&15;
  const bf16x8* Xb = (const bf16x8*)Xbf + (size_t)z*NPTS*8;
  const float* Gz = Gall + z*NPTS;
  double* rowS = z ? rowL : rowK;
  float negi = -1.0f/scal[z];
  double cs[8] = {0,0,0,0,0,0,0,0};
#pragma unroll
  for (int ta=0;ta<2;ta++){
    int rt = w*2+ta;
    float Dv[8][4];
    dtile1(Xb, Gz, i0 + rt*16 + nl, j0, q, nl, Dv);
    double rs[4] = {0,0,0,0};
#pragma unroll
    for (int tb=0;tb<8;tb++){
      int jl = tb*16+nl;
#pragma unroll
      for (int r=0;r<4;r++){
        int il = rt*16+q*4+r;
        float d = Dv[tb][r];
        if (isdiag && il==jl) d = 0.f;      // exact K_ii = 1
        float e = expf(d*negi);
        rs[r] += e; cs[tb] += e;
      }
    }
#pragma unroll
    for (int r=0;r<4;r++){
      double v2 = rs[r];
      v2 += __shfl_xor(v2,1,64); v2 += __shfl_xor(v2,2,64);
      v2 += __shfl_xor(v2,4,64); v2 += __shfl_xor(v2,8,64);
      if (nl==0) atomicAdd(&rowS[i0 + rt*16 + q*4 + r], v2);
    }
  }
  if (!isdiag){
#pragma unroll
    for (int tb=0;tb<8;tb++){
      double v2 = cs[tb];
      v2 += __shfl_xor(v2,16,64); v2 += __shfl_xor(v2,32,64);
      if (q==0) atomicAdd(&rowS[j0 + tb*16 + nl], v2);
    }
  }
}

// ---------- totals of rowK/rowL ----------
__global__ __launch_bounds__(256) void reduce_rows(const double* __restrict__ rowK,
                                                   const double* __restrict__ rowL,
                                                   double* __restrict__ sums){
  __shared__ double sd[256];
  int t=threadIdx.x;
  double s=0; for(int i=t;i<NPTS;i+=256) s+=rowK[i];
  sd[t]=s; __syncthreads();
  for(int off=128;off>0;off>>=1){ if(t<off) sd[t]+=sd[t+off]; __syncthreads(); }
  if(t==0) sums[0]=sd[0];
  __syncthreads();
  s=0; for(int i=t;i<NPTS;i+=256) s+=rowL[i];
  sd[t]=s; __syncthreads();
  for(int off=128;off>0;off>>=1){ if(t<off) sd[t]+=sd[t+off]; __syncthreads(); }
  if(t==0) sums[1]=sd[0];
}

// ---------- pass 3: per-column-group K,L recompute + centered products (no spill) ----------
__global__ __launch_bounds__(256,2) void final_k(const u16* __restrict__ Xbf, const float* __restrict__ Gall,
                                                 const float* __restrict__ scal,
                                                 const double* __restrict__ rowK,
                                                 const double* __restrict__ rowL,
                                                 const double* __restrict__ sums,
                                                 double* __restrict__ partials){
  int b = blockIdx.x, tid = threadIdx.x;
  int by,bx; bmap(b,by,bx);
  bool isdiag = (by==bx);
  int i0=by*TS, j0=bx*TS;
  int w=tid>>6, lane=tid&63, q=lane>>4, nl=lane&15;
  const bf16x8* Xb = (const bf16x8*)Xbf;
  const bf16x8* Yb = Xb + (size_t)NPTS*8;
  const float* Gx = Gall;
  const float* Gy = Gall + NPTS;
  const double inv_n = 1.0/(double)NPTS;
  double tmK = sums[0]*(inv_n*inv_n), tmL = sums[1]*(inv_n*inv_n);
  float negx = -1.0f/scal[0], negy = -1.0f/scal[1];
  double wgt = isdiag ? 1.0 : 2.0;
  double S1=0, S2=0, trV=0;
#pragma unroll
  for (int ta=0;ta<2;ta++){
    int rt = w*2+ta;
    int rowA = i0 + rt*16 + nl;
    bf16x8 axf0 = Xb[(size_t)rowA*8 + q];
    bf16x8 axf1 = Xb[(size_t)rowA*8 + 4 + q];
    bf16x8 ayf0 = Yb[(size_t)rowA*8 + q];
    bf16x8 ayf1 = Yb[(size_t)rowA*8 + 4 + q];
    float gaX = Gx[rowA], gaY = Gy[rowA];
    float gXm[4], gYm[4];
#pragma unroll
    for (int r=0;r<4;r++){ gXm[r] = __shfl(gaX, q*4+r, 64); gYm[r] = __shfl(gaY, q*4+r, 64); }
    double rmKi[4], rmLi[4];
#pragma unroll
    for (int r=0;r<4;r++){
      int i = i0 + rt*16 + q*4 + r;
      rmKi[r] = rowK[i]*inv_n; rmLi[r] = rowL[i]*inv_n;
    }
#pragma unroll
    for (int tb=0;tb<8;tb++){
      int jrow = j0 + tb*16 + nl;
      f32x4 accX = (f32x4)0.0f, accY = (f32x4)0.0f;
      accX = __builtin_amdgcn_mfma_f32_16x16x32_bf16(axf0, Xb[(size_t)jrow*8 + q],     accX, 0,0,0);
      accX = __builtin_amdgcn_mfma_f32_16x16x32_bf16(axf1, Xb[(size_t)jrow*8 + 4 + q], accX, 0,0,0);
      accY = __builtin_amdgcn_mfma_f32_16x16x32_bf16(ayf0, Yb[(size_t)jrow*8 + q],     accY, 0,0,0);
      accY = __builtin_amdgcn_mfma_f32_16x16x32_bf16(ayf1, Yb[(size_t)jrow*8 + 4 + q], accY, 0,0,0);
      float gbX = Gx[jrow], gbY = Gy[jrow];
      double cmK = rowK[jrow]*inv_n - tmK;
      double cmL = rowL[jrow]*inv_n - tmL;
      int jl = tb*16 + nl;
#pragma unroll
      for (int r=0;r<4;r++){
        int il = rt*16 + q*4 + r;
        float dx = (gXm[r] + gbX) - 2.0f*accX[r];
        float dy = (gYm[r] + gbY) - 2.0f*accY[r];
        bool dg = isdiag && il==jl;
        if (dg){ dx = 0.f; dy = 0.f; }
        float kx = expf(dx*negx);
        float lv = expf(dy*negy);
        double kc = ((double)kx - rmKi[r]) - cmK;
        double lc = ((double)lv - rmLi[r]) - cmL;
        double prod = kc*lc;
        S1 += wgt*prod;
        double vv = (prod*prod)*(1.0/36.0);
        S2 += wgt*vv;
        if (dg) trV += vv;
      }
    }
  }
  __shared__ double red[4][3];
  double vals[3]={S1,S2,trV};
  int wv = tid >> 6;
#pragma unroll
  for (int v=0;v<3;v++){
    double x = vals[v];
#pragma unroll
    for (int s2=1;s2<64;s2<<=1) x += __shfl_xor(x, s2, 64);
    if (lane==0) red[wv][v]=x;
  }
  __syncthreads();
  if (tid < 3)
    partials[(size_t)b*4 + tid] = red[0][tid]+red[1][tid]+red[2][tid]+red[3][tid];
}

// ---------- wave-parallel regularized lower incomplete gamma P(a,x) ----------
__device__ double gammainc_wave(double a, double x, double lga, int lane){
  double C = 1.0/a;
  double psum = 0.0;
  for (int b=0;b<8192;b++){
    double k = (double)(b*64 + lane + 1);
    double rr = x/(a+k);
    double pp = rr;
#pragma unroll
    for (int s=1;s<64;s<<=1){
      double t = __shfl_up(pp, s, 64);
      if (lane >= s) pp *= t;
    }
    double c = C*pp;
    psum += c;
    double clast = __shfl(c, 63, 64);
    double rlast = __shfl(rr, 63, 64);
    C = clast;
    if (rlast < 1.0 && clast*rlast/(1.0-rlast) < 1e-17) break;
  }
#pragma unroll
  for (int s=1;s<64;s<<=1) psum += __shfl_xor(psum, s, 64);
  double total = 1.0/a + psum;
  return exp(-x + a*log(x) - lga) * total;
}

// ---------- reduce partials + Newton ----------
__global__ __launch_bounds__(256) void finalize_k(const double* __restrict__ partials,
                                                  const double* __restrict__ sums,
                                                  float* __restrict__ out)
{
  __shared__ double red[3][4];
  __shared__ double tot[4];
  int tid = threadIdx.x;
  double v0=0,v1=0,v2=0;
  for (int i=tid; i<NBLK; i+=256){
    const double* p = partials + (size_t)i*4;
    v0+=p[0]; v1+=p[1]; v2+=p[2];
  }
  double vals[3]={v0,v1,v2};
  int lane = tid & 63, wv = tid >> 6;
#pragma unroll
  for (int v=0;v<3;v++){
    double x = vals[v];
#pragma unroll
    for (int s2=1;s2<64;s2<<=1) x += __shfl_xor(x, s2, 64);
    if (lane==0) red[v][wv]=x;
  }
  __syncthreads();
  if (tid==0){
#pragma unroll
    for (int v=0;v<3;v++) tot[v] = red[v][0]+red[v][1]+red[v][2]+red[v][3];
  }
  __syncthreads();
  if (tid >= 64) return;

  const double n = (double)NPTS;
  double totK=sums[0], totL=sums[1];
  double S1=tot[0], S2=tot[1], trV=tot[2];
  double testStat = S1/n;
  double varHSIC = (S2 - trV)/n/(n-1.0);
  varHSIC = varHSIC*72.0*(n-4.0)*(n-5.0)/n/(n-1.0)/(n-2.0)/(n-3.0);
  double muX = (totK-n)/n/(n-1.0);   // trace(K) = n exactly (diag forced to 1)
  double muY = (totL-n)/n/(n-1.0);
  double mHSIC = (1.0 + muX*muY - muX - muY)/n;
  double al = mHSIC*mHSIC/varHSIC;
  double bet = varHSIC*n/mHSIC;
  double p = (double)((float)(1.0-0.8));
  double lga = lgamma(al);
  double lo = 0.0, hi = al + 10.0*sqrt(al) + 100.0;
  const double zp = -0.8416212335729142957;  // Phi^-1(0.2)
  double t = 1.0 - 1.0/(9.0*al) + zp/(3.0*sqrt(al));
  double x = al*t*t*t;
  if (!(x > 0.0) || !(x < hi)) x = 0.5*hi;
  for (int it=0; it<2; ++it){
    double P = gammainc_wave(al, x, lga, lane);
    double diff = P - p;
    if (diff < 0.0) lo = x; else hi = x;
    if (fabs(diff) < 1e-12) break;
    double pdf = exp(-x + (al-1.0)*log(x) - lga);
    double nx = x - diff/pdf;
    if (!(nx > lo) || !(nx < hi)) nx = 0.5*(lo+hi);
    x = nx;
  }
  if (lane==0){
    out[0]=(float)testStat;
    out[1]=(float)(bet*x);
  }
}

// ---------- host ----------
extern "C" void kernel_launch(void* const* d_in, const int* in_sizes, int n_in,
                              void* d_out, int out_size, void* d_ws, size_t ws_size,
                              hipStream_t stream) {
  const float* X = (const float*)d_in[0];
  const float* Y = (const float*)d_in[1];
  float* out = (float*)d_out;
  char* ws = (char*)d_ws;

  double* sums     = (double*)ws;                    // 2 doubles @0
  float*  scal     = (float*)(ws + 128);             // 2 floats
  u32*    hist16   = (u32*)(ws + 256);               // [2][834] u32 = 6672 B
  double* rowK     = (double*)(ws + 8192);           // 32 KB
  double* rowL     = (double*)(ws + 8192 + 32768);   // 32 KB
  float*  Gall     = (float*)(ws + 73728);           // 2*4096 fp32 = 32 KB
  double* partials = (double*)(ws + 106496);         // 528*4 doubles = 16896 B
  u16*    Xbf      = (u16*)(ws + 131072);            // 2*4096*64 bf16 = 1 MB
  size_t need = 131072 + (size_t)2*NPTS*DIM*2;       // ~1.2 MB

  if (ws_size < need) return;

  hipMemsetAsync(ws + 256, 0, 6672, stream);         // hist16 only

  const u32 K1 = 4193279u, K2 = 4193280u;  // m = 4096*4095/2; median = avg of ranks m/2-1, m/2

  convert_k<<<32,256,0,stream>>>(X, Y, Xbf, Gall);
  hist_k<<<dim3(NBLK,2),256,0,stream>>>(Xbf, Gall, hist16);
  scan16i<<<2,256,0,stream>>>(hist16, scal, rowK, rowL, K1, K2);
  rowsum_k<<<dim3(NBLK,2),256,0,stream>>>(Xbf, Gall, scal, rowK, rowL);
  reduce_rows<<<1,256,0,stream>>>(rowK, rowL, sums);
  final_k<<<NBLK,256,0,stream>>>(Xbf, Gall, scal, rowK, rowL, sums, partials);
  finalize_k<<<1,256,0,stream>>>(partials, sums, out);
}